// Round 3
// baseline (2241.260 us; speedup 1.0000x reference)
//
#include <hip/hip_runtime.h>
#include <hip/hip_bf16.h>
#include <cstdint>

typedef unsigned short u16;
typedef __bf16 bf16x8 __attribute__((ext_vector_type(8)));
typedef float floatx4 __attribute__((ext_vector_type(4)));

// ---- helpers ----------------------------------------------------------------

__device__ __forceinline__ u16 f2bf(float f) {
    union { float f; uint32_t u; } x; x.f = f;
    uint32_t u = x.u;
    u = (u + 0x7FFFu + ((u >> 16) & 1u)) >> 16;   // RNE
    return (u16)u;
}

__device__ __forceinline__ float bf2f(u16 b) {
    union { uint32_t u; float f; } x; x.u = ((uint32_t)b) << 16;
    return x.f;
}

// async global->LDS, 16B per lane; LDS dest is wave-uniform base + lane*16.
__device__ __forceinline__ void load16_to_lds(const u16* g, u16* l) {
    __builtin_amdgcn_global_load_lds(
        (const __attribute__((address_space(1))) unsigned int*)g,
        (__attribute__((address_space(3))) unsigned int*)l, 16, 0, 0);
}

// ---- pack / cast ------------------------------------------------------------

__global__ void pack_pad(const float* __restrict__ src, u16* __restrict__ dst,
                         int src_rows, int src_cols, int pad_cols,
                         int dst_stride, int dst_off, long total) {
    long i = (long)blockIdx.x * blockDim.x + threadIdx.x;
    if (i >= total) return;
    int  col = (int)(i % pad_cols);
    long row = i / pad_cols;
    float v = (row < src_rows && col < src_cols) ? src[row * (long)src_cols + col] : 0.f;
    dst[row * (long)dst_stride + dst_off + col] = f2bf(v);
}

// ---- router -----------------------------------------------------------------

__global__ void router_kernel(const float* __restrict__ x,
                              const float* __restrict__ gw,
                              float* __restrict__ out) {
    const int t = blockIdx.x;
    const int lane = threadIdx.x;
    const float* xr = x + (long)t * 2048;
    float acc[8] = {0.f,0.f,0.f,0.f,0.f,0.f,0.f,0.f};
    for (int k = lane; k < 2048; k += 64) {
        float xv = xr[k];
        #pragma unroll
        for (int e = 0; e < 8; e++) acc[e] += xv * gw[e * 2048 + k];
    }
    #pragma unroll
    for (int off = 32; off > 0; off >>= 1) {
        #pragma unroll
        for (int e = 0; e < 8; e++) acc[e] += __shfl_down(acc[e], off, 64);
    }
    if (lane == 0) {
        #pragma unroll
        for (int e = 0; e < 8; e++) out[(long)t * 8 + e] = acc[e];
    }
}

// ---- gemm_bt: 128x128 tile, BK=32, optional second K-segment ---------------
// EPI: 0 fp32 store, 1 bf16 store, 2 bf16 silu(acc)*Mul, 3 fp32 accumulate

template <int EPI>
__global__ __launch_bounds__(256)
void gemm_bt(const u16* __restrict__ A, int lda,
             const u16* __restrict__ B, int ldb,
             void* __restrict__ C, int ldc,
             const u16* __restrict__ Mul, int ldmul, int K,
             const u16* __restrict__ A2, int lda2,
             const u16* __restrict__ B2, int ldb2, int K2) {
    __shared__ u16 sA[128 * 32];
    __shared__ u16 sB[128 * 32];

    const int tid  = threadIdx.x;
    const int wave = tid >> 6;
    const int lane = tid & 63;
    const int l15  = lane & 15;
    const int lq   = lane >> 4;
    const int wm   = wave >> 1;
    const int wn   = wave & 1;
    const long rowBase = (long)blockIdx.y * 128;
    const long colBase = (long)blockIdx.x * 128;

    floatx4 acc[4][4] = {};

    const u16* gA[2]; const u16* gB[2];
    u16* lA[2]; u16* lB[2];
    #pragma unroll
    for (int i = 0; i < 2; i++) {
        int lin = i * 256 + tid;
        int row = lin >> 2;
        int kc  = lin & 3;
        gA[i] = A + (rowBase + row) * (long)lda + kc * 8;
        gB[i] = B + (colBase + row) * (long)ldb + kc * 8;
        int base = (i * 256 + wave * 64) * 8;
        lA[i] = &sA[base];
        lB[i] = &sB[base];
    }

    const int nk = K >> 5;
    for (int kt = 0; kt < nk; kt++) {
        const long ko = (long)kt * 32;
        #pragma unroll
        for (int i = 0; i < 2; i++) {
            load16_to_lds(gA[i] + ko, lA[i]);
            load16_to_lds(gB[i] + ko, lB[i]);
        }
        __syncthreads();
        bf16x8 af[4], bb[4];
        #pragma unroll
        for (int i = 0; i < 4; i++)
            af[i] = *(const bf16x8*)&sA[(wm * 64 + i * 16 + l15) * 32 + lq * 8];
        #pragma unroll
        for (int j = 0; j < 4; j++)
            bb[j] = *(const bf16x8*)&sB[(wn * 64 + j * 16 + l15) * 32 + lq * 8];
        #pragma unroll
        for (int i = 0; i < 4; i++)
            #pragma unroll
            for (int j = 0; j < 4; j++)
                acc[i][j] = __builtin_amdgcn_mfma_f32_16x16x32_bf16(af[i], bb[j], acc[i][j], 0, 0, 0);
        __syncthreads();
    }

    if (K2 > 0) {
        const u16* gA2[2]; const u16* gB2[2];
        #pragma unroll
        for (int i = 0; i < 2; i++) {
            int lin = i * 256 + tid;
            int row = lin >> 2;
            int kc  = lin & 3;
            gA2[i] = A2 + (rowBase + row) * (long)lda2 + kc * 8;
            gB2[i] = B2 + (colBase + row) * (long)ldb2 + kc * 8;
        }
        const int nk2 = K2 >> 5;
        for (int kt = 0; kt < nk2; kt++) {
            const long ko = (long)kt * 32;
            #pragma unroll
            for (int i = 0; i < 2; i++) {
                load16_to_lds(gA2[i] + ko, lA[i]);
                load16_to_lds(gB2[i] + ko, lB[i]);
            }
            __syncthreads();
            bf16x8 af[4], bb[4];
            #pragma unroll
            for (int i = 0; i < 4; i++)
                af[i] = *(const bf16x8*)&sA[(wm * 64 + i * 16 + l15) * 32 + lq * 8];
            #pragma unroll
            for (int j = 0; j < 4; j++)
                bb[j] = *(const bf16x8*)&sB[(wn * 64 + j * 16 + l15) * 32 + lq * 8];
            #pragma unroll
            for (int i = 0; i < 4; i++)
                #pragma unroll
                for (int j = 0; j < 4; j++)
                    acc[i][j] = __builtin_amdgcn_mfma_f32_16x16x32_bf16(af[i], bb[j], acc[i][j], 0, 0, 0);
            __syncthreads();
        }
    }

    #pragma unroll
    for (int i = 0; i < 4; i++) {
        long row0 = rowBase + wm * 64 + i * 16 + lq * 4;
        #pragma unroll
        for (int j = 0; j < 4; j++) {
            long col = colBase + wn * 64 + j * 16 + l15;
            #pragma unroll
            for (int r = 0; r < 4; r++) {
                float v = acc[i][j][r];
                long idx = (row0 + r) * (long)ldc + col;
                if (EPI == 0) {
                    ((float*)C)[idx] = v;
                } else if (EPI == 1) {
                    ((u16*)C)[idx] = f2bf(v);
                } else if (EPI == 2) {
                    float u = bf2f(Mul[(row0 + r) * (long)ldmul + col]);
                    float s = v / (1.f + __expf(-v));
                    ((u16*)C)[idx] = f2bf(s * u);
                } else {
                    ((float*)C)[idx] += v;
                }
            }
        }
    }
}

// ---- gemm_nb: 128Mx64N tile, BK=32; DUAL = two B matrices + in-reg silu ----
// DUAL: C = silu(A@B2^T) * (A@B1^T) with phased K:
//   tiles [0,ktSh): both (shared A cols, B cols = same)
//   tiles [ktSh, ktSh+ktEx): B1 only (A cols continue, B1 cols continue)
//   tiles [ktSh+ktEx, ktSh+2*ktEx): B2 only (A cols continue, B2 cols = ktSh..)
// !DUAL: plain C = A@B1^T (bf16 store), ktEx ignored.

template <bool DUAL>
__global__ __launch_bounds__(256)
void gemm_nb(const u16* __restrict__ A, int lda,
             const u16* __restrict__ B1, int ldb1,
             const u16* __restrict__ B2, int ldb2,
             u16* __restrict__ C, int ldc,
             int ktSh, int ktEx) {
    __shared__ u16 sA[128 * 32];
    __shared__ u16 sB1[64 * 32];
    __shared__ u16 sB2[64 * 32];

    const int tid  = threadIdx.x;
    const int wave = tid >> 6;
    const int lane = tid & 63;
    const int l15  = lane & 15;
    const int lq   = lane >> 4;
    const int wm   = wave >> 1;          // 0..1: 64-row half
    const int wn   = wave & 1;           // 0..1: 32-col half
    const long rowBase = (long)blockIdx.y * 128;
    const long colBase = (long)blockIdx.x * 64;

    floatx4 au[4][2] = {};
    floatx4 ag[4][2] = {};

    const u16* gA[2]; u16* lA[2];
    #pragma unroll
    for (int i = 0; i < 2; i++) {
        int lin = i * 256 + tid;
        int row = lin >> 2;
        int kc  = lin & 3;
        gA[i] = A + (rowBase + row) * (long)lda + kc * 8;
        lA[i] = &sA[(i * 256 + wave * 64) * 8];
    }
    const int brow = tid >> 2;
    const int bkc  = tid & 3;
    const u16* gB1 = B1 + (colBase + brow) * (long)ldb1 + bkc * 8;
    const u16* gB2 = B2 + (colBase + brow) * (long)ldb2 + bkc * 8;
    u16* lB1 = &sB1[wave * 512];
    u16* lB2 = &sB2[wave * 512];

    const int kt1End = ktSh + ktEx;
    const int ktTot  = DUAL ? ktSh + 2 * ktEx : ktSh;

    for (int kt = 0; kt < ktTot; kt++) {
        const bool d1 = !DUAL || kt < kt1End;
        const bool d2 = DUAL && (kt < ktSh || kt >= kt1End);
        const long aO = (long)kt * 32;
        load16_to_lds(gA[0] + aO, lA[0]);
        load16_to_lds(gA[1] + aO, lA[1]);
        if (d1) load16_to_lds(gB1 + aO, lB1);
        if (d2) load16_to_lds(gB2 + (long)(kt < ktSh ? kt : kt - ktEx) * 32, lB2);
        __syncthreads();

        bf16x8 af[4];
        #pragma unroll
        for (int i = 0; i < 4; i++)
            af[i] = *(const bf16x8*)&sA[(wm * 64 + i * 16 + l15) * 32 + lq * 8];
        if (d1) {
            bf16x8 bb[2];
            #pragma unroll
            for (int j = 0; j < 2; j++)
                bb[j] = *(const bf16x8*)&sB1[(wn * 32 + j * 16 + l15) * 32 + lq * 8];
            #pragma unroll
            for (int i = 0; i < 4; i++)
                #pragma unroll
                for (int j = 0; j < 2; j++)
                    au[i][j] = __builtin_amdgcn_mfma_f32_16x16x32_bf16(af[i], bb[j], au[i][j], 0, 0, 0);
        }
        if constexpr (DUAL) {
            if (d2) {
                bf16x8 bb[2];
                #pragma unroll
                for (int j = 0; j < 2; j++)
                    bb[j] = *(const bf16x8*)&sB2[(wn * 32 + j * 16 + l15) * 32 + lq * 8];
                #pragma unroll
                for (int i = 0; i < 4; i++)
                    #pragma unroll
                    for (int j = 0; j < 2; j++)
                        ag[i][j] = __builtin_amdgcn_mfma_f32_16x16x32_bf16(af[i], bb[j], ag[i][j], 0, 0, 0);
            }
        }
        __syncthreads();
    }

    #pragma unroll
    for (int i = 0; i < 4; i++) {
        long row0 = rowBase + wm * 64 + i * 16 + lq * 4;
        #pragma unroll
        for (int j = 0; j < 2; j++) {
            long col = colBase + wn * 32 + j * 16 + l15;
            #pragma unroll
            for (int r = 0; r < 4; r++) {
                float u = au[i][j][r];
                if constexpr (DUAL) {
                    float g = ag[i][j][r];
                    u = u * (g / (1.f + __expf(-g)));
                }
                C[(row0 + r) * (long)ldc + col] = f2bf(u);
            }
        }
    }
}

// ---- launch -----------------------------------------------------------------

static inline void launch_pack(const float* src, u16* dst, int sr, int sc,
                               int pr, int pc, int stride, int off,
                               hipStream_t stream) {
    long total = (long)pr * pc;
    int blocks = (int)((total + 255) / 256);
    hipLaunchKernelGGL(pack_pad, dim3(blocks), dim3(256), 0, stream,
                       src, dst, sr, sc, pc, stride, off, total);
}

extern "C" void kernel_launch(void* const* d_in, const int* in_sizes, int n_in,
                              void* d_out, int out_size, void* d_ws, size_t ws_size,
                              hipStream_t stream) {
    const float* x      = (const float*)d_in[0];
    const float* gate_w = (const float*)d_in[1];
    const float* w1     = (const float*)d_in[2];
    const float* w2     = (const float*)d_in[3];
    const float* w3     = (const float*)d_in[4];
    const float* u1     = (const float*)d_in[5];
    const float* v1     = (const float*)d_in[6];
    const float* u2     = (const float*)d_in[7];
    const float* v2     = (const float*)d_in[8];
    const float* u3     = (const float*)d_in[9];
    const float* v3     = (const float*)d_in[10];

    float* out    = (float*)d_out;
    float* logits = out + 16777216L;

    hipLaunchKernelGGL(router_kernel, dim3(8192), dim3(64), 0, stream,
                       x, gate_w, logits);

    if (ws_size >= 235274240ULL) {
        // ================= fused path, peak 235.3 MB =================
        // XT [8192,2880] = [Xb(2048) | T3(416) | T1(416)]
        // WU [7168,2464] = [w3 | u3p];  WG [7168,2464] = [w1 | u1p]
        // H  [8192,7168]
        u16* XT = (u16*)d_ws;              // 23,592,960
        u16* WU = XT + 23592960L;          // 17,661,952
        u16* WG = WU + 17661952L;          // 17,661,952
        u16* H  = WG + 17661952L;          // 58,720,256
        u16* VB = WU;                      // [832,2048] transient (dead before WU pack)
        u16* T2 = XT;                      // [8192,448] after gemm23 (XT dead)
        u16* V2P = WU;                     // [448,7168]
        u16* W2B = V2P + 448L * 7168;      // [2048,7168]
        u16* U2P = W2B + 2048L * 7168;     // [2048,448]

        launch_pack(x,  XT, 8192, 2048, 8192, 2048, 2880, 0, stream);
        launch_pack(v3, VB, 398, 2048, 416, 2048, 2048, 0, stream);
        launch_pack(v1, VB + 416L * 2048, 398, 2048, 416, 2048, 2048, 0, stream);

        // T3|T1 = Xb @ [v3p;v1p]^T -> XT cols [2048,2880)
        hipLaunchKernelGGL((gemm_nb<false>), dim3(13, 64), dim3(256), 0, stream,
                           XT, 2880, VB, 2048, VB, 2048, XT + 2048, 2880, 64, 0);

        launch_pack(w3, WU, 7168, 2048, 7168, 2048, 2464, 0, stream);
        launch_pack(u3, WU, 7168, 398, 7168, 416, 2464, 2048, stream);
        launch_pack(w1, WG, 7168, 2048, 7168, 2048, 2464, 0, stream);
        launch_pack(u1, WG, 7168, 398, 7168, 416, 2464, 2048, stream);

        // H = silu(XT @ WG^T) * (XT @ WU^T), phased K (64 shared + 13 + 13)
        hipLaunchKernelGGL((gemm_nb<true>), dim3(112, 64), dim3(256), 0, stream,
                           XT, 2880, WU, 2464, WG, 2464, H, 7168, 64, 13);

        launch_pack(v2, V2P, 398, 7168, 448, 7168, 7168, 0, stream);
        launch_pack(w2, W2B, 2048, 7168, 2048, 7168, 7168, 0, stream);
        launch_pack(u2, U2P, 2048, 398, 2048, 448, 448, 0, stream);

        // T2 = H @ v2p^T  [8192,448]
        hipLaunchKernelGGL((gemm_nb<false>), dim3(7, 64), dim3(256), 0, stream,
                           H, 7168, V2P, 7168, V2P, 7168, T2, 448, 224, 0);

        // out = H @ w2b^T + T2 @ u2p^T (two K-segments, fp32 store)
        hipLaunchKernelGGL((gemm_bt<0>), dim3(16, 64), dim3(256), 0, stream,
                           H, 7168, W2B, 7168, (void*)out, 2048,
                           (const u16*)nullptr, 0, 7168,
                           T2, 448, U2P, 448, 448);
    } else {
        // ================= fallback: round-2 proven path (206.6 MB) ==========
        u16* XT = (u16*)d_ws;
        u16* WR = XT + 25165824L;
        u16* UB = WR + 19398656L;
        u16* T2 = XT;
        u16* V3P = WR;
        u16* V1P = WR + 512L * 2048;
        u16* WU  = WR;
        u16* WG  = WR;
        u16* V2P = WR;
        u16* W2B = WR + 512L * 7168;
        u16* U2P = W2B + 2048L * 7168;

        launch_pack(x,  XT + 512, 8192, 2048, 8192, 2048, 3072, 0, stream);
        launch_pack(v3, V3P, 398, 2048, 512, 2048, 2048, 0, stream);
        launch_pack(v1, V1P, 398, 2048, 512, 2048, 2048, 0, stream);

        hipLaunchKernelGGL((gemm_bt<1>), dim3(4, 64), dim3(256), 0, stream,
                           XT + 512, 3072, V3P, 2048, (void*)XT, 3072,
                           (const u16*)nullptr, 0, 2048,
                           (const u16*)nullptr, 0, (const u16*)nullptr, 0, 0);
        hipLaunchKernelGGL((gemm_bt<1>), dim3(4, 64), dim3(256), 0, stream,
                           XT + 512, 3072, V1P, 2048, (void*)(XT + 2560), 3072,
                           (const u16*)nullptr, 0, 2048,
                           (const u16*)nullptr, 0, (const u16*)nullptr, 0, 0);

        launch_pack(u3, WU, 7168, 398, 7168, 512, 2560, 0, stream);
        launch_pack(w3, WU, 7168, 2048, 7168, 2048, 2560, 512, stream);

        hipLaunchKernelGGL((gemm_bt<1>), dim3(56, 64), dim3(256), 0, stream,
                           XT, 3072, WU, 2560, (void*)UB, 7168,
                           (const u16*)nullptr, 0, 2560,
                           (const u16*)nullptr, 0, (const u16*)nullptr, 0, 0);

        launch_pack(w1, WG, 7168, 2048, 7168, 2048, 2560, 0, stream);
        launch_pack(u1, WG, 7168, 398, 7168, 512, 2560, 2048, stream);

        hipLaunchKernelGGL((gemm_bt<2>), dim3(56, 64), dim3(256), 0, stream,
                           XT + 512, 3072, WG, 2560, (void*)UB, 7168,
                           UB, 7168, 2560,
                           (const u16*)nullptr, 0, (const u16*)nullptr, 0, 0);

        launch_pack(v2, V2P, 398, 7168, 512, 7168, 7168, 0, stream);
        launch_pack(w2, W2B, 2048, 7168, 2048, 7168, 7168, 0, stream);
        launch_pack(u2, U2P, 2048, 398, 2048, 512, 512, 0, stream);

        hipLaunchKernelGGL((gemm_bt<1>), dim3(4, 64), dim3(256), 0, stream,
                           UB, 7168, V2P, 7168, (void*)T2, 512,
                           (const u16*)nullptr, 0, 7168,
                           (const u16*)nullptr, 0, (const u16*)nullptr, 0, 0);
        hipLaunchKernelGGL((gemm_bt<0>), dim3(16, 64), dim3(256), 0, stream,
                           UB, 7168, W2B, 7168, (void*)out, 2048,
                           (const u16*)nullptr, 0, 7168,
                           (const u16*)nullptr, 0, (const u16*)nullptr, 0, 0);
        hipLaunchKernelGGL((gemm_bt<3>), dim3(16, 64), dim3(256), 0, stream,
                           T2, 512, U2P, 512, (void*)out, 2048,
                           (const u16*)nullptr, 0, 512,
                           (const u16*)nullptr, 0, (const u16*)nullptr, 0, 0);
    }
}